// Round 8
// baseline (12747.601 us; speedup 1.0000x reference)
//
#include <hip/hip_runtime.h>
#include <stdint.h>

typedef unsigned int u32;

#define DEV __device__ __forceinline__
#define BN_EPS 1e-5f

// ---------------------------------------------------------------- ws-too-small fallback
__global__ void kfb(float* out, int n, float code){
  int i = blockIdx.x * 256 + threadIdx.x;
  if (i < n) out[i] = (i == 0) ? code : 0.f;
}

// ---------------------------------------------------------------- stage A: BN1 stats (deterministic)
__global__ __launch_bounds__(256) void kA_stats(const float* __restrict__ x, const float* __restrict__ w,
                                                const float* __restrict__ g, const float* __restrict__ b,
                                                float* __restrict__ sc, float* __restrict__ sh){
  int c = blockIdx.x, t = threadIdx.x;
  float wr[6];
#pragma unroll
  for (int j = 0; j < 6; ++j) wr[j] = w[c * 6 + j];
  float s = 0.f, ss = 0.f;
  for (int i = t; i < 32768; i += 256){
    int bb = i >> 10, n = i & 1023;
    const float* xb = x + bb * 6144 + n;
    float y = 0.f;
#pragma unroll
    for (int j = 0; j < 6; ++j) y += wr[j] * xb[j * 1024];
    s += y; ss += y * y;
  }
  __shared__ float rs[256], rq[256];
  rs[t] = s; rq[t] = ss; __syncthreads();
  for (int k = 128; k >= 1; k >>= 1){
    if (t < k){ rs[t] += rs[t + k]; rq[t] += rq[t + k]; }
    __syncthreads();
  }
  if (t == 0){
    float m = rs[0] * (1.f / 32768.f), e2 = rq[0] * (1.f / 32768.f);
    float var = e2 - m * m; if (var < 0.f) var = 0.f;
    float scv = g[c] * rsqrtf(var + BN_EPS);
    sc[c] = scv; sh[c] = b[c] - m * scv;
  }
}

// stage A apply -> featT f32 [b][n][64]
__global__ __launch_bounds__(256) void kA_feat(const float* __restrict__ x, const float* __restrict__ w,
                                               const float* __restrict__ sc, const float* __restrict__ sh,
                                               float* __restrict__ featT){
  int b = blockIdx.x >> 2, t = threadIdx.x;
  int n = ((blockIdx.x & 3) << 8) + t;
  __shared__ float wl[384], scl[64], shl[64];
  for (int u = t; u < 384; u += 256) wl[u] = w[u];   // FIX: was `if (t < 384)` with 256 threads
  if (t < 64){ scl[t] = sc[t]; shl[t] = sh[t]; }
  __syncthreads();
  float v[6];
  const float* xb = x + b * 6144 + n;
#pragma unroll
  for (int j = 0; j < 6; ++j) v[j] = xb[j * 1024];
  float* row = featT + ((size_t)b * 1024 + n) * 64;
#pragma unroll
  for (int c = 0; c < 64; ++c){
    float y = 0.f;
#pragma unroll
    for (int j = 0; j < 6; ++j) y += wl[c * 6 + j] * v[j];
    y = scl[c] * y + shl[c];
    row[c] = fmaxf(y, 0.f);
  }
}

// ---------------------------------------------------------------- x_skip pre-act f32 [b][1024][256]
__global__ __launch_bounds__(256) void kxskip_pre(const float* __restrict__ featT, const float* __restrict__ w2,
                                                  float* __restrict__ xpre){
  int b = blockIdx.x >> 8, m = blockIdx.x & 255, t = threadIdx.x;
  __shared__ float row[64];
  if (t < 64) row[t] = featT[((size_t)b * 1024 + 4 * m) * 64 + t];
  __syncthreads();
#pragma unroll
  for (int rep = 0; rep < 4; ++rep){
    int o = rep * 256 + t;
    float acc = 0.f;
    const float* wr = w2 + (size_t)o * 64;
#pragma unroll
    for (int c = 0; c < 64; ++c) acc += wr[c] * row[c];
    xpre[((size_t)b * 1024 + o) * 256 + m] = acc;
  }
}

__global__ __launch_bounds__(256) void kxskip_stats(const float* __restrict__ xpre, const float* __restrict__ g,
                                                    const float* __restrict__ b, float* __restrict__ sc,
                                                    float* __restrict__ sh){
  int o = blockIdx.x, t = threadIdx.x;
  float s = 0.f, ss = 0.f;
  for (int i = t; i < 8192; i += 256){
    int bb = i >> 8, m = i & 255;
    float v = xpre[((size_t)bb * 1024 + o) * 256 + m];
    s += v; ss += v * v;
  }
  __shared__ float rs[256], rq[256];
  rs[t] = s; rq[t] = ss; __syncthreads();
  for (int k = 128; k >= 1; k >>= 1){
    if (t < k){ rs[t] += rs[t + k]; rq[t] += rq[t + k]; }
    __syncthreads();
  }
  if (t == 0){
    float m = rs[0] * (1.f / 8192.f), e2 = rq[0] * (1.f / 8192.f);
    float var = e2 - m * m; if (var < 0.f) var = 0.f;
    float scv = g[o] * rsqrtf(var + BN_EPS);
    sc[o] = scv; sh[o] = b[o] - m * scv;
  }
}

// ---------------------------------------------------------------- FPS f32 (serial scan, np order; validated vs f64 in R6)
template<int NPTS, int NSAMP, int PSTRIDE>
__global__ __launch_bounds__(64) void kfps32(const float* __restrict__ px_, const float* __restrict__ py_,
                                             const float* __restrict__ pz_, int bstride,
                                             int* __restrict__ fidx, float* __restrict__ nxyz){
  constexpr int PPL = NPTS / 64;
  __shared__ float sx[NPTS], sy[NPTS], sz[NPTS];
  __shared__ float sbd[64];
  __shared__ u32 sbi[64];
  __shared__ float scc[3];
  int b = blockIdx.x, lane = threadIdx.x;
  float dd[PPL];
#pragma unroll
  for (int j = 0; j < PPL; ++j){
    int p = j * 64 + lane;
    sx[p] = px_[(size_t)b * bstride + p * PSTRIDE];
    sy[p] = py_[(size_t)b * bstride + p * PSTRIDE];
    sz[p] = pz_[(size_t)b * bstride + p * PSTRIDE];
    dd[j] = 1e10f;
  }
  __syncthreads();
  if (lane == 0){
    scc[0] = sx[0]; scc[1] = sy[0]; scc[2] = sz[0];
    fidx[(size_t)b * NSAMP] = 0;
    nxyz[(size_t)b * NSAMP * 3 + 0] = sx[0];
    nxyz[(size_t)b * NSAMP * 3 + 1] = sy[0];
    nxyz[(size_t)b * NSAMP * 3 + 2] = sz[0];
  }
  __syncthreads();
  for (int s = 1; s < NSAMP; ++s){
    float cx = scc[0], cy = scc[1], cz = scc[2];
    float bd = -1.f; u32 bi = 0;
#pragma unroll
    for (int j = 0; j < PPL; ++j){
      int p = j * 64 + lane;
      float dx = __fsub_rn(sx[p], cx);
      float dy = __fsub_rn(sy[p], cy);
      float dz = __fsub_rn(sz[p], cz);
      float d = __fadd_rn(__fadd_rn(__fmul_rn(dx, dx), __fmul_rn(dy, dy)), __fmul_rn(dz, dz));
      float nd = fminf(dd[j], d);
      dd[j] = nd;
      if (nd > bd){ bd = nd; bi = (u32)p; }
    }
    sbd[lane] = bd; sbi[lane] = bi;
    __syncthreads();
    if (lane == 0){
      float Bd = sbd[0]; u32 Bi = sbi[0];
      for (int l = 1; l < 64; ++l){
        if (sbd[l] > Bd || (sbd[l] == Bd && sbi[l] < Bi)){ Bd = sbd[l]; Bi = sbi[l]; }
      }
      scc[0] = sx[Bi]; scc[1] = sy[Bi]; scc[2] = sz[Bi];
      fidx[(size_t)b * NSAMP + s] = (int)Bi;
      nxyz[((size_t)b * NSAMP + s) * 3 + 0] = sx[Bi];
      nxyz[((size_t)b * NSAMP + s) * 3 + 1] = sy[Bi];
      nxyz[((size_t)b * NSAMP + s) * 3 + 2] = sz[Bi];
    }
    __syncthreads();
  }
}

// ---------------------------------------------------------------- kNN f32 (serial, np order; validated vs f64 in R6)
template<int NPTS, int SOUT>
__global__ __launch_bounds__(64) void kknn32(const float* __restrict__ px_, const float* __restrict__ py_,
                                             const float* __restrict__ pz_, int bstride, int pstride,
                                             const float* __restrict__ cxyz, int* __restrict__ knn){
  constexpr int PPL = NPTS / 64;
  int wid = blockIdx.x, lane = threadIdx.x;
  int b = wid / SOUT, s = wid - b * SOUT;
  const float* cb = cxyz + ((size_t)b * SOUT + s) * 3;
  float cx = cb[0], cy = cb[1], cz = cb[2];
  float csq = __fadd_rn(__fadd_rn(__fmul_rn(cx, cx), __fmul_rn(cy, cy)), __fmul_rn(cz, cz));
  float kd[PPL]; u32 kp[PPL];
#pragma unroll
  for (int j = 0; j < PPL; ++j){
    int p = j * 64 + lane;
    float xx = px_[(size_t)b * bstride + p * pstride];
    float yy = py_[(size_t)b * bstride + p * pstride];
    float zz = pz_[(size_t)b * bstride + p * pstride];
    float psq = __fadd_rn(__fadd_rn(__fmul_rn(xx, xx), __fmul_rn(yy, yy)), __fmul_rn(zz, zz));
    float dot = __fadd_rn(__fadd_rn(__fmul_rn(cx, xx), __fmul_rn(cy, yy)), __fmul_rn(cz, zz));
    kd[j] = __fsub_rn(__fadd_rn(csq, psq), __fmul_rn(2.f, dot));
    kp[j] = (u32)p;
  }
  __shared__ float sbd[64];
  __shared__ u32 sbi[64];
  __shared__ u32 swin;
  int* outp = knn + ((size_t)b * SOUT + s) * 32;
  for (int k = 0; k < 32; ++k){
    float bd = kd[0]; u32 bp = kp[0];
#pragma unroll
    for (int j = 1; j < PPL; ++j){
      if (kd[j] < bd){ bd = kd[j]; bp = kp[j]; }
    }
    sbd[lane] = bd; sbi[lane] = bp;
    __syncthreads();
    if (lane == 0){
      float Bd = sbd[0]; u32 Bi = sbi[0];
      for (int l = 1; l < 64; ++l){
        if (sbd[l] < Bd || (sbd[l] == Bd && sbi[l] < Bi)){ Bd = sbd[l]; Bi = sbi[l]; }
      }
      swin = Bi;
      outp[k] = (int)Bi;
    }
    __syncthreads();
    u32 w = swin;
#pragma unroll
    for (int j = 0; j < PPL; ++j) if (kp[j] == w) kd[j] = 3e38f;
    __syncthreads();
  }
}

// ---------------------------------------------------------------- local_op pass 1: GEMM1 pre-acts (LDS) -> per-group BN1 partials
template<int LC, int COUT, int NPTSRC, int SLOG>
__global__ __launch_bounds__(256) void kg1stats(const float* __restrict__ featSrc, const int* __restrict__ knn,
                                                const int* __restrict__ fidx, const float* __restrict__ w1,
                                                float* __restrict__ part){
  constexpr int CIN = 1 << LC;
  int g = blockIdx.x, t = threadIdx.x, b = g >> SLOG;
  __shared__ int idxs[32];
  __shared__ float grp[32][CIN + 1];
  __shared__ float cen[CIN];
  __shared__ float pre[COUT][32];
  if (t < 32) idxs[t] = knn[(size_t)g * 32 + t];
  __syncthreads();
  for (int u = t; u < 32 * CIN; u += 256){
    int k = u >> LC, c = u & (CIN - 1);
    grp[k][c] = featSrc[((size_t)(b * NPTSRC + idxs[k])) * CIN + c];
  }
  {
    int ci = fidx[g];
    for (int u = t; u < CIN; u += 256) cen[u] = featSrc[((size_t)(b * NPTSRC + ci)) * CIN + u];
  }
  __syncthreads();
  for (int u = t; u < COUT * 32; u += 256){
    int o = u >> 5, k = u & 31;
    const float* wr = w1 + (size_t)o * (2 * CIN);
    float acc = 0.f;
#pragma unroll 8
    for (int c = 0; c < CIN; ++c) acc += wr[c] * (grp[k][c] - cen[c]);
#pragma unroll 8
    for (int c = 0; c < CIN; ++c) acc += wr[CIN + c] * cen[c];
    pre[o][k] = acc;
  }
  __syncthreads();
  if (t < COUT){
    float s = 0.f, ss = 0.f;
#pragma unroll
    for (int k = 0; k < 32; ++k){ float v = pre[t][k]; s += v; ss += v * v; }
    part[((size_t)g * COUT + t) * 2 + 0] = s;
    part[((size_t)g * COUT + t) * 2 + 1] = ss;
  }
}

// reduce per-group partials -> BN scale/shift (deterministic)
template<int C, int NG>
__global__ __launch_bounds__(256) void kstats_part(const float* __restrict__ part, const float* __restrict__ g_,
                                                   const float* __restrict__ b_, float* __restrict__ sc,
                                                   float* __restrict__ sh){
  int o = blockIdx.x, t = threadIdx.x;
  float s = 0.f, ss = 0.f;
  for (int i = t; i < NG; i += 256){
    s  += part[((size_t)i * C + o) * 2 + 0];
    ss += part[((size_t)i * C + o) * 2 + 1];
  }
  __shared__ float rs[256], rq[256];
  rs[t] = s; rq[t] = ss; __syncthreads();
  for (int k = 128; k >= 1; k >>= 1){
    if (t < k){ rs[t] += rs[t + k]; rq[t] += rq[t + k]; }
    __syncthreads();
  }
  if (t == 0){
    const float inv_n = 1.f / (float)(NG * 32);
    float m = rs[0] * inv_n, e2 = rq[0] * inv_n;
    float var = e2 - m * m; if (var < 0.f) var = 0.f;
    float scv = g_[o] * rsqrtf(var + BN_EPS);
    sc[o] = scv; sh[o] = b_[o] - m * scv;
  }
}

// ---------------------------------------------------------------- local_op pass 2: recompute GEMM1, BN1+ReLU, GEMM2 + partials + pool
template<int LC, int C, int NPTSRC, int SLOG>
__global__ __launch_bounds__(256) void kg2full(const float* __restrict__ featSrc, const int* __restrict__ knn,
                                               const int* __restrict__ fidx, const float* __restrict__ w1,
                                               const float* __restrict__ sc1, const float* __restrict__ sh1,
                                               const float* __restrict__ w2, const float* __restrict__ gp,
                                               float* __restrict__ part, float* __restrict__ pooledPre){
  constexpr int CIN = 1 << LC;
  int g = blockIdx.x, t = threadIdx.x, b = g >> SLOG;
  __shared__ int idxs[32];
  __shared__ float grp[32][CIN + 1];
  __shared__ float cen[CIN];
  __shared__ float pre[C][32];
  if (t < 32) idxs[t] = knn[(size_t)g * 32 + t];
  __syncthreads();
  for (int u = t; u < 32 * CIN; u += 256){
    int k = u >> LC, c = u & (CIN - 1);
    grp[k][c] = featSrc[((size_t)(b * NPTSRC + idxs[k])) * CIN + c];
  }
  {
    int ci = fidx[g];
    for (int u = t; u < CIN; u += 256) cen[u] = featSrc[((size_t)(b * NPTSRC + ci)) * CIN + u];
  }
  __syncthreads();
  for (int u = t; u < C * 32; u += 256){
    int o = u >> 5, k = u & 31;
    const float* wr = w1 + (size_t)o * (2 * CIN);
    float acc = 0.f;
#pragma unroll 8
    for (int c = 0; c < CIN; ++c) acc += wr[c] * (grp[k][c] - cen[c]);
#pragma unroll 8
    for (int c = 0; c < CIN; ++c) acc += wr[CIN + c] * cen[c];
    pre[o][k] = acc;
  }
  __syncthreads();
  // BN1 + ReLU in place
  for (int u = t; u < C * 32; u += 256){
    int o = u >> 5, k = u & 31;
    pre[o][k] = fmaxf(sc1[o] * pre[o][k] + sh1[o], 0.f);
  }
  __syncthreads();
  if (t < C){
    float a[32];
#pragma unroll
    for (int k = 0; k < 32; ++k) a[k] = 0.f;
    const float* wr = w2 + (size_t)t * C;
    for (int c = 0; c < C; ++c){
      float wv = wr[c];
#pragma unroll
      for (int k = 0; k < 32; ++k) a[k] += wv * pre[c][k];
    }
    float s = 0.f, ss = 0.f, mx = -3e38f, mn = 3e38f;
#pragma unroll
    for (int k = 0; k < 32; ++k){
      float v = a[k];
      s += v; ss += v * v; mx = fmaxf(mx, v); mn = fminf(mn, v);
    }
    part[((size_t)g * C + t) * 2 + 0] = s;
    part[((size_t)g * C + t) * 2 + 1] = ss;
    pooledPre[(size_t)g * C + t] = (gp[t] >= 0.f) ? mx : mn;
  }
}

// finalize pooled (stage1): f0feat f32 [b*512+s][128]
__global__ void kpool_fin1(const float* __restrict__ pooledPre, const float* __restrict__ sc,
                           const float* __restrict__ sh, float* __restrict__ f0feat){
  int i = blockIdx.x * 256 + threadIdx.x;
  if (i >= 16384 * 128) return;
  int o = i & 127;
  float v = sc[o] * pooledPre[i] + sh[o];
  f0feat[i] = fmaxf(v, 0.f);
}

// finalize pooled (stage2): f1T f32 [b][c][s]
__global__ void kpool_finT(const float* __restrict__ pooledPre, const float* __restrict__ sc,
                           const float* __restrict__ sh, float* __restrict__ f1T){
  int i = blockIdx.x * 256 + threadIdx.x;
  if (i >= 8192 * 256) return;
  int gg = i >> 8, o = i & 255;
  int b = gg >> 8, s = gg & 255;
  float v = sc[o] * pooledPre[i] + sh[o];
  f1T[((size_t)(b * 256 + o)) * 256 + s] = fmaxf(v, 0.f);
}

// ---------------------------------------------------------------- final GEMM (f32)
__global__ __launch_bounds__(256) void kfinaln(const float* __restrict__ f1T, const float* __restrict__ xpre,
                                               const float* __restrict__ scS, const float* __restrict__ shS,
                                               const float* __restrict__ wf, float* __restrict__ finpre){
  int b = blockIdx.x >> 9, o = blockIdx.x & 511, m = threadIdx.x;
  __shared__ float wsh[1280];
  __shared__ float scl[1024], shl[1024];
  for (int u = threadIdx.x; u < 1280; u += 256) wsh[u] = wf[(size_t)o * 1280 + u];
  for (int u = threadIdx.x; u < 1024; u += 256){ scl[u] = scS[u]; shl[u] = shS[u]; }
  __syncthreads();
  float acc = 0.f;
  for (int k = 0; k < 256; ++k)
    acc += wsh[k] * f1T[((size_t)b * 256 + k) * 256 + m];
  for (int k = 0; k < 1024; ++k){
    float v = scl[k] * xpre[((size_t)b * 1024 + k) * 256 + m] + shl[k];
    acc += wsh[256 + k] * fmaxf(v, 0.f);
  }
  finpre[((size_t)b * 512 + o) * 256 + m] = acc;
}

__global__ __launch_bounds__(256) void kstats_fin(const float* __restrict__ finpre, const float* __restrict__ g,
                                                  const float* __restrict__ b, float* __restrict__ sc,
                                                  float* __restrict__ sh){
  int o = blockIdx.x, t = threadIdx.x;
  float s = 0.f, ss = 0.f;
  for (int i = t; i < 8192; i += 256){
    int bb = i >> 8, m = i & 255;
    float v = finpre[((size_t)bb * 512 + o) * 256 + m];
    s += v; ss += v * v;
  }
  __shared__ float rs[256], rq[256];
  rs[t] = s; rq[t] = ss; __syncthreads();
  for (int k = 128; k >= 1; k >>= 1){
    if (t < k){ rs[t] += rs[t + k]; rq[t] += rq[t + k]; }
    __syncthreads();
  }
  if (t == 0){
    float m = rs[0] * (1.f / 8192.f), e2 = rq[0] * (1.f / 8192.f);
    float var = e2 - m * m; if (var < 0.f) var = 0.f;
    float scv = g[o] * rsqrtf(var + BN_EPS);
    sc[o] = scv; sh[o] = b[o] - m * scv;
  }
}

__global__ void kapply(const float* __restrict__ finpre, const float* __restrict__ sc,
                       const float* __restrict__ sh, float* __restrict__ out){
  int i = blockIdx.x * 256 + threadIdx.x;
  if (i >= 32 * 512 * 256) return;
  int o = (i >> 8) & 511;
  float v = sc[o] * finpre[i] + sh[o];
  out[i] = v > 0.f ? v : 0.2f * v;
}

// ================================================================ host
extern "C" void kernel_launch(void* const* d_in, const int* in_sizes, int n_in,
                              void* d_out, int out_size, void* d_ws, size_t ws_size,
                              hipStream_t stream){
  const float* x    = (const float*)d_in[0];
  const float* w_c1 = (const float*)d_in[1];
  const float* g1   = (const float*)d_in[2];
  const float* b1   = (const float*)d_in[3];
  const float* w_c2 = (const float*)d_in[4];
  const float* g2   = (const float*)d_in[5];
  const float* b2   = (const float*)d_in[6];
  const float* l0w1 = (const float*)d_in[7];
  const float* l0g1 = (const float*)d_in[8];
  const float* l0b1 = (const float*)d_in[9];
  const float* l0w2 = (const float*)d_in[10];
  const float* l0g2 = (const float*)d_in[11];
  const float* l0b2 = (const float*)d_in[12];
  const float* l1w1 = (const float*)d_in[13];
  const float* l1g1 = (const float*)d_in[14];
  const float* l1b1 = (const float*)d_in[15];
  const float* l1w2 = (const float*)d_in[16];
  const float* l1g2 = (const float*)d_in[17];
  const float* l1b2 = (const float*)d_in[18];
  const float* wf   = (const float*)d_in[19];
  const float* gf   = (const float*)d_in[20];
  const float* bfp  = (const float*)d_in[21];
  float* out = (float*)d_out;

  char* ws = (char*)d_ws;
  size_t cur = 0;
  auto alloc = [&](size_t bytes) -> char* {
    char* p = ws + cur;
    cur += (bytes + 255) & ~(size_t)255;
    return p;
  };
  float* sc1  = (float*)alloc(64 * 4);    float* sh1  = (float*)alloc(64 * 4);
  float* scSK = (float*)alloc(1024 * 4);  float* shSK = (float*)alloc(1024 * 4);
  float* scA1 = (float*)alloc(128 * 4);   float* shA1 = (float*)alloc(128 * 4);
  float* scA2 = (float*)alloc(128 * 4);   float* shA2 = (float*)alloc(128 * 4);
  float* scC1 = (float*)alloc(256 * 4);   float* shC1 = (float*)alloc(256 * 4);
  float* scC2 = (float*)alloc(256 * 4);   float* shC2 = (float*)alloc(256 * 4);
  float* scF  = (float*)alloc(512 * 4);   float* shF  = (float*)alloc(512 * 4);
  float* featT  = (float*)alloc((size_t)32 * 1024 * 64 * 4);
  float* xpre   = (float*)alloc((size_t)32 * 1024 * 256 * 4);
  int*   fidx1  = (int*)  alloc((size_t)32 * 512 * 4);
  float* nxyz1  = (float*)alloc((size_t)32 * 512 * 3 * 4);
  int*   knn1   = (int*)  alloc((size_t)32 * 512 * 32 * 4);
  int*   fidx2  = (int*)  alloc((size_t)32 * 256 * 4);
  float* nxyz2  = (float*)alloc((size_t)32 * 256 * 3 * 4);
  int*   knn2   = (int*)  alloc((size_t)32 * 256 * 32 * 4);
  float* part   = (float*)alloc((size_t)16384 * 128 * 2 * 4);  // == 8192*256*2, reused by stage 2
  float* pooledPre = (float*)alloc((size_t)16384 * 128 * 4);   // == 8192*256, reused by stage 2
  float* f0feat = (float*)alloc((size_t)16384 * 128 * 4);
  float* f1T    = (float*)alloc((size_t)32 * 256 * 256 * 4);
  float* finpre = (float*)alloc((size_t)32 * 512 * 256 * 4);

  if (cur > ws_size){
    float code = -1000.f - (float)(ws_size >> 20);
    kfb<<<(out_size + 255) / 256, 256, 0, stream>>>(out, out_size, code);
    return;
  }

  // stage A
  kA_stats<<<64, 256, 0, stream>>>(x, w_c1, g1, b1, sc1, sh1);
  kA_feat<<<128, 256, 0, stream>>>(x, w_c1, sc1, sh1, featT);

  // x_skip
  kxskip_pre<<<8192, 256, 0, stream>>>(featT, w_c2, xpre);
  kxskip_stats<<<1024, 256, 0, stream>>>(xpre, g2, b2, scSK, shSK);

  // stage 1 selections
  kfps32<1024, 512, 1><<<32, 64, 0, stream>>>(x, x + 1024, x + 2048, 6144, fidx1, nxyz1);
  kknn32<1024, 512><<<32 * 512, 64, 0, stream>>>(x, x + 1024, x + 2048, 6144, 1, nxyz1, knn1);

  // stage 1 local_op (two-pass, f32, deterministic)
  kg1stats<6, 128, 1024, 9><<<16384, 256, 0, stream>>>(featT, knn1, fidx1, l0w1, part);
  kstats_part<128, 16384><<<128, 256, 0, stream>>>(part, l0g1, l0b1, scA1, shA1);
  kg2full<6, 128, 1024, 9><<<16384, 256, 0, stream>>>(featT, knn1, fidx1, l0w1, scA1, shA1, l0w2, l0g2, part, pooledPre);
  kstats_part<128, 16384><<<128, 256, 0, stream>>>(part, l0g2, l0b2, scA2, shA2);
  kpool_fin1<<<8192, 256, 0, stream>>>(pooledPre, scA2, shA2, f0feat);

  // stage 2 selections
  kfps32<512, 256, 3><<<32, 64, 0, stream>>>(nxyz1, nxyz1 + 1, nxyz1 + 2, 1536, fidx2, nxyz2);
  kknn32<512, 256><<<32 * 256, 64, 0, stream>>>(nxyz1, nxyz1 + 1, nxyz1 + 2, 1536, 3, nxyz2, knn2);

  // stage 2 local_op
  kg1stats<7, 256, 512, 8><<<8192, 256, 0, stream>>>(f0feat, knn2, fidx2, l1w1, part);
  kstats_part<256, 8192><<<256, 256, 0, stream>>>(part, l1g1, l1b1, scC1, shC1);
  kg2full<7, 256, 512, 8><<<8192, 256, 0, stream>>>(f0feat, knn2, fidx2, l1w1, scC1, shC1, l1w2, l1g2, part, pooledPre);
  kstats_part<256, 8192><<<256, 256, 0, stream>>>(part, l1g2, l1b2, scC2, shC2);
  kpool_finT<<<8192, 256, 0, stream>>>(pooledPre, scC2, shC2, f1T);

  // final
  kfinaln<<<16384, 256, 0, stream>>>(f1T, xpre, scSK, shSK, wf, finpre);
  kstats_fin<<<512, 256, 0, stream>>>(finpre, gf, bfp, scF, shF);
  kapply<<<16384, 256, 0, stream>>>(finpre, scF, shF, out);
}

// Round 9
// 3999.478 us; speedup vs baseline: 3.1873x; 3.1873x over previous
//
#include <hip/hip_runtime.h>
#include <stdint.h>

typedef unsigned int u32;

#define DEV __device__ __forceinline__
#define BN_EPS 1e-5f

// ---------------------------------------------------------------- ws-too-small fallback
__global__ void kfb(float* out, int n, float code){
  int i = blockIdx.x * 256 + threadIdx.x;
  if (i < n) out[i] = (i == 0) ? code : 0.f;
}

// transpose: dst[c*rows + r] = src[r*srcStride + colOff + c], r<rows, c<cols
__global__ void kprepT(const float* __restrict__ src, int rows, int cols, int srcStride, int colOff,
                       float* __restrict__ dst){
  int i = blockIdx.x * 256 + threadIdx.x;
  if (i >= rows * cols) return;
  int r = i / cols, c = i - r * cols;
  dst[c * rows + r] = src[r * srcStride + colOff + c];
}

// ---------------------------------------------------------------- stage A: BN1 stats (deterministic)
__global__ __launch_bounds__(256) void kA_stats(const float* __restrict__ x, const float* __restrict__ w,
                                                const float* __restrict__ g, const float* __restrict__ b,
                                                float* __restrict__ sc, float* __restrict__ sh){
  int c = blockIdx.x, t = threadIdx.x;
  float wr[6];
#pragma unroll
  for (int j = 0; j < 6; ++j) wr[j] = w[c * 6 + j];
  float s = 0.f, ss = 0.f;
  for (int i = t; i < 32768; i += 256){
    int bb = i >> 10, n = i & 1023;
    const float* xb = x + bb * 6144 + n;
    float y = 0.f;
#pragma unroll
    for (int j = 0; j < 6; ++j) y += wr[j] * xb[j * 1024];
    s += y; ss += y * y;
  }
  __shared__ float rs[256], rq[256];
  rs[t] = s; rq[t] = ss; __syncthreads();
  for (int k = 128; k >= 1; k >>= 1){
    if (t < k){ rs[t] += rs[t + k]; rq[t] += rq[t + k]; }
    __syncthreads();
  }
  if (t == 0){
    float m = rs[0] * (1.f / 32768.f), e2 = rq[0] * (1.f / 32768.f);
    float var = e2 - m * m; if (var < 0.f) var = 0.f;
    float scv = g[c] * rsqrtf(var + BN_EPS);
    sc[c] = scv; sh[c] = b[c] - m * scv;
  }
}

// stage A apply -> featT f32 [b][n][64]
__global__ __launch_bounds__(256) void kA_feat(const float* __restrict__ x, const float* __restrict__ w,
                                               const float* __restrict__ sc, const float* __restrict__ sh,
                                               float* __restrict__ featT){
  int b = blockIdx.x >> 2, t = threadIdx.x;
  int n = ((blockIdx.x & 3) << 8) + t;
  __shared__ float wl[384], scl[64], shl[64];
  for (int u = t; u < 384; u += 256) wl[u] = w[u];
  if (t < 64){ scl[t] = sc[t]; shl[t] = sh[t]; }
  __syncthreads();
  float v[6];
  const float* xb = x + b * 6144 + n;
#pragma unroll
  for (int j = 0; j < 6; ++j) v[j] = xb[j * 1024];
  float* row = featT + ((size_t)b * 1024 + n) * 64;
#pragma unroll
  for (int c = 0; c < 64; ++c){
    float y = 0.f;
#pragma unroll
    for (int j = 0; j < 6; ++j) y += wl[c * 6 + j] * v[j];
    y = scl[c] * y + shl[c];
    row[c] = fmaxf(y, 0.f);
  }
}

// ---------------------------------------------------------------- x_skip pre-act f32 [b][1024][256]
__global__ __launch_bounds__(256) void kxskip_pre(const float* __restrict__ featT, const float* __restrict__ w2,
                                                  float* __restrict__ xpre){
  int b = blockIdx.x >> 8, m = blockIdx.x & 255, t = threadIdx.x;
  __shared__ float row[64];
  if (t < 64) row[t] = featT[((size_t)b * 1024 + 4 * m) * 64 + t];
  __syncthreads();
#pragma unroll
  for (int rep = 0; rep < 4; ++rep){
    int o = rep * 256 + t;
    float acc = 0.f;
    const float* wr = w2 + (size_t)o * 64;
#pragma unroll
    for (int c = 0; c < 64; ++c) acc += wr[c] * row[c];
    xpre[((size_t)b * 1024 + o) * 256 + m] = acc;
  }
}

__global__ __launch_bounds__(256) void kxskip_stats(const float* __restrict__ xpre, const float* __restrict__ g,
                                                    const float* __restrict__ b, float* __restrict__ sc,
                                                    float* __restrict__ sh){
  int o = blockIdx.x, t = threadIdx.x;
  float s = 0.f, ss = 0.f;
  for (int i = t; i < 8192; i += 256){
    int bb = i >> 8, m = i & 255;
    float v = xpre[((size_t)bb * 1024 + o) * 256 + m];
    s += v; ss += v * v;
  }
  __shared__ float rs[256], rq[256];
  rs[t] = s; rq[t] = ss; __syncthreads();
  for (int k = 128; k >= 1; k >>= 1){
    if (t < k){ rs[t] += rs[t + k]; rq[t] += rq[t + k]; }
    __syncthreads();
  }
  if (t == 0){
    float m = rs[0] * (1.f / 8192.f), e2 = rq[0] * (1.f / 8192.f);
    float var = e2 - m * m; if (var < 0.f) var = 0.f;
    float scv = g[o] * rsqrtf(var + BN_EPS);
    sc[o] = scv; sh[o] = b[o] - m * scv;
  }
}

// ---------------------------------------------------------------- FPS: wave butterfly, f32 np-order
// (wave==serial validated R4; f32==f64 picks validated R6)
template<int NPTS, int NSAMP, int PSTRIDE>
__global__ __launch_bounds__(64) void kfps(const float* __restrict__ px_, const float* __restrict__ py_,
                                           const float* __restrict__ pz_, int bstride,
                                           int* __restrict__ fidx, float* __restrict__ nxyz){
  constexpr int PPL = NPTS / 64;
  int b = blockIdx.x, lane = threadIdx.x;
  const float* pxb = px_ + (size_t)b * bstride;
  const float* pyb = py_ + (size_t)b * bstride;
  const float* pzb = pz_ + (size_t)b * bstride;
  float px[PPL], py[PPL], pz[PPL], dd[PPL];
#pragma unroll
  for (int j = 0; j < PPL; ++j){
    int p = j * 64 + lane;
    px[j] = pxb[p * PSTRIDE]; py[j] = pyb[p * PSTRIDE]; pz[j] = pzb[p * PSTRIDE];
    dd[j] = 1e10f;
  }
  float cx = __shfl(px[0], 0, 64), cy = __shfl(py[0], 0, 64), cz = __shfl(pz[0], 0, 64);
  if (lane == 0){
    fidx[(size_t)b * NSAMP] = 0;
    nxyz[(size_t)b * NSAMP * 3 + 0] = cx;
    nxyz[(size_t)b * NSAMP * 3 + 1] = cy;
    nxyz[(size_t)b * NSAMP * 3 + 2] = cz;
  }
  for (int s = 1; s < NSAMP; ++s){
    float bd = -1.f; u32 bi = 0;
#pragma unroll
    for (int j = 0; j < PPL; ++j){
      float dx = __fsub_rn(px[j], cx);
      float dy = __fsub_rn(py[j], cy);
      float dz = __fsub_rn(pz[j], cz);
      float d = __fadd_rn(__fadd_rn(__fmul_rn(dx, dx), __fmul_rn(dy, dy)), __fmul_rn(dz, dz));
      float nd = fminf(dd[j], d);
      dd[j] = nd;
      u32 pi = (u32)(j * 64 + lane);
      if (nd > bd || (nd == bd && pi < bi)){ bd = nd; bi = pi; }
    }
#pragma unroll
    for (int o = 32; o >= 1; o >>= 1){
      float od = __shfl_xor(bd, o, 64);
      u32 oi = __shfl_xor(bi, o, 64);
      if (od > bd || (od == bd && oi < bi)){ bd = od; bi = oi; }
    }
    int wl = (int)(bi & 63u); int slot = (int)(bi >> 6);
    float sx = 0.f, sy = 0.f, sz = 0.f;
#pragma unroll
    for (int j = 0; j < PPL; ++j) if (slot == j){ sx = px[j]; sy = py[j]; sz = pz[j]; }
    cx = __shfl(sx, wl, 64); cy = __shfl(sy, wl, 64); cz = __shfl(sz, wl, 64);
    if (lane == 0){
      fidx[(size_t)b * NSAMP + s] = (int)bi;
      nxyz[((size_t)b * NSAMP + s) * 3 + 0] = cx;
      nxyz[((size_t)b * NSAMP + s) * 3 + 1] = cy;
      nxyz[((size_t)b * NSAMP + s) * 3 + 2] = cz;
    }
  }
}

// ---------------------------------------------------------------- kNN: wave butterfly, 1 wave/query, 4 waves/block
template<int NPTS, int SOUT>
__global__ __launch_bounds__(256) void kknn(const float* __restrict__ px_, const float* __restrict__ py_,
                                            const float* __restrict__ pz_, int bstride, int pstride,
                                            const float* __restrict__ cxyz, int* __restrict__ knn){
  constexpr int PPL = NPTS / 64;
  int wid = blockIdx.x * 4 + (threadIdx.x >> 6);
  int lane = threadIdx.x & 63;
  int b = wid / SOUT, s = wid - b * SOUT;
  const float* cb = cxyz + ((size_t)b * SOUT + s) * 3;
  float cx = cb[0], cy = cb[1], cz = cb[2];
  float csq = __fadd_rn(__fadd_rn(__fmul_rn(cx, cx), __fmul_rn(cy, cy)), __fmul_rn(cz, cz));
  float kd[PPL]; u32 kp[PPL];
#pragma unroll
  for (int j = 0; j < PPL; ++j){
    int p = j * 64 + lane;
    float xx = px_[(size_t)b * bstride + p * pstride];
    float yy = py_[(size_t)b * bstride + p * pstride];
    float zz = pz_[(size_t)b * bstride + p * pstride];
    float psq = __fadd_rn(__fadd_rn(__fmul_rn(xx, xx), __fmul_rn(yy, yy)), __fmul_rn(zz, zz));
    float dot = __fadd_rn(__fadd_rn(__fmul_rn(cx, xx), __fmul_rn(cy, yy)), __fmul_rn(cz, zz));
    kd[j] = __fsub_rn(__fadd_rn(csq, psq), __fmul_rn(2.f, dot));
    kp[j] = (u32)p;
  }
  int* outp = knn + ((size_t)b * SOUT + s) * 32;
  for (int k = 0; k < 32; ++k){
    float bd = kd[0]; u32 bp = kp[0];
#pragma unroll
    for (int j = 1; j < PPL; ++j){
      if (kd[j] < bd || (kd[j] == bd && kp[j] < bp)){ bd = kd[j]; bp = kp[j]; }
    }
#pragma unroll
    for (int o = 32; o >= 1; o >>= 1){
      float od = __shfl_xor(bd, o, 64);
      u32 op = __shfl_xor(bp, o, 64);
      if (od < bd || (od == bd && op < bp)){ bd = od; bp = op; }
    }
    if (lane == 0) outp[k] = (int)bp;
#pragma unroll
    for (int j = 0; j < PPL; ++j) if (kp[j] == bp) kd[j] = 3e38f;
  }
}

// ---------------------------------------------------------------- shared GEMM1 building block (register-tiled)
// gsT[c][k] = gathered - center (transposed); bias[o] = sum_c w1[o][CIN+c]*cen[c]
// out[o][k] = bias[o] + sum_c w1lT[c][o]*gsT[c][k]

// pass 1: GEMM1 -> per-group BN1 partial sums (no LDS round-trip of pre)
template<int CIN, int COUT, int NPTSRC, int SLOG>
__global__ __launch_bounds__(256) void kg1stats(const float* __restrict__ featSrc, const int* __restrict__ knn,
                                                const int* __restrict__ fidx, const float* __restrict__ w1,
                                                const float* __restrict__ w1lT, float* __restrict__ part){
  constexpr int OPT = COUT / 32;
  int g = blockIdx.x, t = threadIdx.x, b = g >> SLOG;
  int tk = t & 7, to = t >> 3;
  __shared__ int idxs[32];
  __shared__ float cen[CIN];
  __shared__ float gsT[CIN][32];
  __shared__ float bias[COUT];
  if (t < 32) idxs[t] = knn[(size_t)g * 32 + t];
  for (int u = t; u < CIN; u += 256) cen[u] = featSrc[((size_t)(b * NPTSRC + fidx[g])) * CIN + u];
  __syncthreads();
  for (int u = t; u < 32 * CIN / 4; u += 256){
    int k = u & 31, c4 = u >> 5;
    float4 v = *(const float4*)(featSrc + ((size_t)(b * NPTSRC + idxs[k])) * CIN + c4 * 4);
    gsT[c4 * 4 + 0][k] = v.x - cen[c4 * 4 + 0];
    gsT[c4 * 4 + 1][k] = v.y - cen[c4 * 4 + 1];
    gsT[c4 * 4 + 2][k] = v.z - cen[c4 * 4 + 2];
    gsT[c4 * 4 + 3][k] = v.w - cen[c4 * 4 + 3];
  }
  if (t < COUT){
    const float* wr = w1 + (size_t)t * (2 * CIN) + CIN;
    float bsum = 0.f;
#pragma unroll 4
    for (int c = 0; c < CIN; ++c) bsum += wr[c] * cen[c];
    bias[t] = bsum;
  }
  __syncthreads();
  float acc[OPT][4];
#pragma unroll
  for (int oi = 0; oi < OPT; ++oi){
    float bv = bias[to * OPT + oi];
#pragma unroll
    for (int ki = 0; ki < 4; ++ki) acc[oi][ki] = bv;
  }
  for (int c = 0; c < CIN; ++c){
    float4 gv = *(const float4*)&gsT[c][tk * 4];
    const float4* wrow = (const float4*)(w1lT + (size_t)c * COUT + to * OPT);
#pragma unroll
    for (int oq = 0; oq < OPT / 4; ++oq){
      float4 wv = wrow[oq];
      const float* wfp = (const float*)&wv;
#pragma unroll
      for (int oo = 0; oo < 4; ++oo){
        int oi = oq * 4 + oo;
        acc[oi][0] = fmaf(wfp[oo], gv.x, acc[oi][0]);
        acc[oi][1] = fmaf(wfp[oo], gv.y, acc[oi][1]);
        acc[oi][2] = fmaf(wfp[oo], gv.z, acc[oi][2]);
        acc[oi][3] = fmaf(wfp[oo], gv.w, acc[oi][3]);
      }
    }
  }
#pragma unroll
  for (int oi = 0; oi < OPT; ++oi){
    int o = to * OPT + oi;
    float s = 0.f, ss = 0.f;
#pragma unroll
    for (int ki = 0; ki < 4; ++ki){ float v = acc[oi][ki]; s += v; ss += v * v; }
#pragma unroll
    for (int d = 1; d < 8; d <<= 1){ s += __shfl_xor(s, d, 64); ss += __shfl_xor(ss, d, 64); }
    if (tk == 0){
      part[((size_t)g * COUT + o) * 2 + 0] = s;
      part[((size_t)g * COUT + o) * 2 + 1] = ss;
    }
  }
}

// reduce per-group partials -> BN scale/shift (deterministic)
template<int C, int NG>
__global__ __launch_bounds__(256) void kstats_part(const float* __restrict__ part, const float* __restrict__ g_,
                                                   const float* __restrict__ b_, float* __restrict__ sc,
                                                   float* __restrict__ sh){
  int o = blockIdx.x, t = threadIdx.x;
  float s = 0.f, ss = 0.f;
  for (int i = t; i < NG; i += 256){
    s  += part[((size_t)i * C + o) * 2 + 0];
    ss += part[((size_t)i * C + o) * 2 + 1];
  }
  __shared__ float rs[256], rq[256];
  rs[t] = s; rq[t] = ss; __syncthreads();
  for (int k = 128; k >= 1; k >>= 1){
    if (t < k){ rs[t] += rs[t + k]; rq[t] += rq[t + k]; }
    __syncthreads();
  }
  if (t == 0){
    const float inv_n = 1.f / (float)(NG * 32);
    float m = rs[0] * inv_n, e2 = rq[0] * inv_n;
    float var = e2 - m * m; if (var < 0.f) var = 0.f;
    float scv = g_[o] * rsqrtf(var + BN_EPS);
    sc[o] = scv; sh[o] = b_[o] - m * scv;
  }
}

// pass 2: recompute GEMM1 (reg-tiled) -> BN1+ReLU in regs -> actT LDS -> GEMM2 (reg-tiled) -> partials + pool
template<int CIN, int C, int NPTSRC, int SLOG>
__global__ __launch_bounds__(256) void kg2full(const float* __restrict__ featSrc, const int* __restrict__ knn,
                                               const int* __restrict__ fidx, const float* __restrict__ w1,
                                               const float* __restrict__ w1lT,
                                               const float* __restrict__ sc1, const float* __restrict__ sh1,
                                               const float* __restrict__ w2T, const float* __restrict__ gp,
                                               float* __restrict__ part, float* __restrict__ pooledPre){
  constexpr int OPT = C / 32;
  int g = blockIdx.x, t = threadIdx.x, b = g >> SLOG;
  int tk = t & 7, to = t >> 3;
  __shared__ int idxs[32];
  __shared__ float cen[CIN];
  __shared__ float gsT[CIN][32];
  __shared__ float bias[C];
  __shared__ float actT[C][32];
  if (t < 32) idxs[t] = knn[(size_t)g * 32 + t];
  for (int u = t; u < CIN; u += 256) cen[u] = featSrc[((size_t)(b * NPTSRC + fidx[g])) * CIN + u];
  __syncthreads();
  for (int u = t; u < 32 * CIN / 4; u += 256){
    int k = u & 31, c4 = u >> 5;
    float4 v = *(const float4*)(featSrc + ((size_t)(b * NPTSRC + idxs[k])) * CIN + c4 * 4);
    gsT[c4 * 4 + 0][k] = v.x - cen[c4 * 4 + 0];
    gsT[c4 * 4 + 1][k] = v.y - cen[c4 * 4 + 1];
    gsT[c4 * 4 + 2][k] = v.z - cen[c4 * 4 + 2];
    gsT[c4 * 4 + 3][k] = v.w - cen[c4 * 4 + 3];
  }
  if (t < C){
    const float* wr = w1 + (size_t)t * (2 * CIN) + CIN;
    float bsum = 0.f;
#pragma unroll 4
    for (int c = 0; c < CIN; ++c) bsum += wr[c] * cen[c];
    bias[t] = bsum;
  }
  __syncthreads();
  float acc[OPT][4];
#pragma unroll
  for (int oi = 0; oi < OPT; ++oi){
    float bv = bias[to * OPT + oi];
#pragma unroll
    for (int ki = 0; ki < 4; ++ki) acc[oi][ki] = bv;
  }
  for (int c = 0; c < CIN; ++c){
    float4 gv = *(const float4*)&gsT[c][tk * 4];
    const float4* wrow = (const float4*)(w1lT + (size_t)c * C + to * OPT);
#pragma unroll
    for (int oq = 0; oq < OPT / 4; ++oq){
      float4 wv = wrow[oq];
      const float* wfp = (const float*)&wv;
#pragma unroll
      for (int oo = 0; oo < 4; ++oo){
        int oi = oq * 4 + oo;
        acc[oi][0] = fmaf(wfp[oo], gv.x, acc[oi][0]);
        acc[oi][1] = fmaf(wfp[oo], gv.y, acc[oi][1]);
        acc[oi][2] = fmaf(wfp[oo], gv.z, acc[oi][2]);
        acc[oi][3] = fmaf(wfp[oo], gv.w, acc[oi][3]);
      }
    }
  }
  // BN1 + ReLU in registers, write actT[o][k]
#pragma unroll
  for (int oi = 0; oi < OPT; ++oi){
    int o = to * OPT + oi;
    float s1 = sc1[o], h1 = sh1[o];
    float4 av;
    av.x = fmaxf(s1 * acc[oi][0] + h1, 0.f);
    av.y = fmaxf(s1 * acc[oi][1] + h1, 0.f);
    av.z = fmaxf(s1 * acc[oi][2] + h1, 0.f);
    av.w = fmaxf(s1 * acc[oi][3] + h1, 0.f);
    *(float4*)&actT[o][tk * 4] = av;
  }
  __syncthreads();
  // GEMM2
  float acc2[OPT][4];
#pragma unroll
  for (int oi = 0; oi < OPT; ++oi)
#pragma unroll
    for (int ki = 0; ki < 4; ++ki) acc2[oi][ki] = 0.f;
  for (int c = 0; c < C; ++c){
    float4 av = *(const float4*)&actT[c][tk * 4];
    const float4* wrow = (const float4*)(w2T + (size_t)c * C + to * OPT);
#pragma unroll
    for (int oq = 0; oq < OPT / 4; ++oq){
      float4 wv = wrow[oq];
      const float* wfp = (const float*)&wv;
#pragma unroll
      for (int oo = 0; oo < 4; ++oo){
        int oi = oq * 4 + oo;
        acc2[oi][0] = fmaf(wfp[oo], av.x, acc2[oi][0]);
        acc2[oi][1] = fmaf(wfp[oo], av.y, acc2[oi][1]);
        acc2[oi][2] = fmaf(wfp[oo], av.z, acc2[oi][2]);
        acc2[oi][3] = fmaf(wfp[oo], av.w, acc2[oi][3]);
      }
    }
  }
#pragma unroll
  for (int oi = 0; oi < OPT; ++oi){
    int o = to * OPT + oi;
    float s = 0.f, ss = 0.f, mx = -3e38f, mn = 3e38f;
#pragma unroll
    for (int ki = 0; ki < 4; ++ki){
      float v = acc2[oi][ki];
      s += v; ss += v * v; mx = fmaxf(mx, v); mn = fminf(mn, v);
    }
#pragma unroll
    for (int d = 1; d < 8; d <<= 1){
      s += __shfl_xor(s, d, 64); ss += __shfl_xor(ss, d, 64);
      mx = fmaxf(mx, __shfl_xor(mx, d, 64)); mn = fminf(mn, __shfl_xor(mn, d, 64));
    }
    if (tk == 0){
      part[((size_t)g * C + o) * 2 + 0] = s;
      part[((size_t)g * C + o) * 2 + 1] = ss;
      pooledPre[(size_t)g * C + o] = (gp[o] >= 0.f) ? mx : mn;
    }
  }
}

// finalize pooled (stage1): f0feat f32 [b*512+s][128]
__global__ void kpool_fin1(const float* __restrict__ pooledPre, const float* __restrict__ sc,
                           const float* __restrict__ sh, float* __restrict__ f0feat){
  int i = blockIdx.x * 256 + threadIdx.x;
  if (i >= 16384 * 128) return;
  int o = i & 127;
  float v = sc[o] * pooledPre[i] + sh[o];
  f0feat[i] = fmaxf(v, 0.f);
}

// finalize pooled (stage2): f1T f32 [b][c][s]
__global__ void kpool_finT(const float* __restrict__ pooledPre, const float* __restrict__ sc,
                           const float* __restrict__ sh, float* __restrict__ f1T){
  int i = blockIdx.x * 256 + threadIdx.x;
  if (i >= 8192 * 256) return;
  int gg = i >> 8, o = i & 255;
  int b = gg >> 8, s = gg & 255;
  float v = sc[o] * pooledPre[i] + sh[o];
  f1T[((size_t)(b * 256 + o)) * 256 + s] = fmaxf(v, 0.f);
}

// ---------------------------------------------------------------- final GEMM: block = (b, 8-o tile), thread = m
// weight / scale reads are wave-uniform -> scalar loads, no LDS
__global__ __launch_bounds__(256) void kfinal8(const float* __restrict__ f1T, const float* __restrict__ xpre,
                                               const float* __restrict__ scS, const float* __restrict__ shS,
                                               const float* __restrict__ wf, float* __restrict__ finpre){
  int b = blockIdx.x >> 6, ot = blockIdx.x & 63, m = threadIdx.x;
  int o0 = ot * 8;
  const float* wb = wf + (size_t)o0 * 1280;
  float acc[8];
#pragma unroll
  for (int j = 0; j < 8; ++j) acc[j] = 0.f;
  const float* fb = f1T + (size_t)b * 256 * 256 + m;
  for (int k = 0; k < 256; ++k){
    float v = fb[(size_t)k * 256];
#pragma unroll
    for (int j = 0; j < 8; ++j) acc[j] = fmaf(wb[(size_t)j * 1280 + k], v, acc[j]);
  }
  const float* xb = xpre + (size_t)b * 1024 * 256 + m;
  for (int k = 0; k < 1024; ++k){
    float xv = xb[(size_t)k * 256];
    float v = fmaxf(scS[k] * xv + shS[k], 0.f);
#pragma unroll
    for (int j = 0; j < 8; ++j) acc[j] = fmaf(wb[(size_t)j * 1280 + 256 + k], v, acc[j]);
  }
#pragma unroll
  for (int j = 0; j < 8; ++j)
    finpre[((size_t)b * 512 + o0 + j) * 256 + m] = acc[j];
}

__global__ __launch_bounds__(256) void kstats_fin(const float* __restrict__ finpre, const float* __restrict__ g,
                                                  const float* __restrict__ b, float* __restrict__ sc,
                                                  float* __restrict__ sh){
  int o = blockIdx.x, t = threadIdx.x;
  float s = 0.f, ss = 0.f;
  for (int i = t; i < 8192; i += 256){
    int bb = i >> 8, m = i & 255;
    float v = finpre[((size_t)bb * 512 + o) * 256 + m];
    s += v; ss += v * v;
  }
  __shared__ float rs[256], rq[256];
  rs[t] = s; rq[t] = ss; __syncthreads();
  for (int k = 128; k >= 1; k >>= 1){
    if (t < k){ rs[t] += rs[t + k]; rq[t] += rq[t + k]; }
    __syncthreads();
  }
  if (t == 0){
    float m = rs[0] * (1.f / 8192.f), e2 = rq[0] * (1.f / 8192.f);
    float var = e2 - m * m; if (var < 0.f) var = 0.f;
    float scv = g[o] * rsqrtf(var + BN_EPS);
    sc[o] = scv; sh[o] = b[o] - m * scv;
  }
}

__global__ void kapply(const float* __restrict__ finpre, const float* __restrict__ sc,
                       const float* __restrict__ sh, float* __restrict__ out){
  int i = blockIdx.x * 256 + threadIdx.x;
  if (i >= 32 * 512 * 256) return;
  int o = (i >> 8) & 511;
  float v = sc[o] * finpre[i] + sh[o];
  out[i] = v > 0.f ? v : 0.2f * v;
}

// ================================================================ host
extern "C" void kernel_launch(void* const* d_in, const int* in_sizes, int n_in,
                              void* d_out, int out_size, void* d_ws, size_t ws_size,
                              hipStream_t stream){
  const float* x    = (const float*)d_in[0];
  const float* w_c1 = (const float*)d_in[1];
  const float* g1   = (const float*)d_in[2];
  const float* b1   = (const float*)d_in[3];
  const float* w_c2 = (const float*)d_in[4];
  const float* g2   = (const float*)d_in[5];
  const float* b2   = (const float*)d_in[6];
  const float* l0w1 = (const float*)d_in[7];
  const float* l0g1 = (const float*)d_in[8];
  const float* l0b1 = (const float*)d_in[9];
  const float* l0w2 = (const float*)d_in[10];
  const float* l0g2 = (const float*)d_in[11];
  const float* l0b2 = (const float*)d_in[12];
  const float* l1w1 = (const float*)d_in[13];
  const float* l1g1 = (const float*)d_in[14];
  const float* l1b1 = (const float*)d_in[15];
  const float* l1w2 = (const float*)d_in[16];
  const float* l1g2 = (const float*)d_in[17];
  const float* l1b2 = (const float*)d_in[18];
  const float* wf   = (const float*)d_in[19];
  const float* gf   = (const float*)d_in[20];
  const float* bfp  = (const float*)d_in[21];
  float* out = (float*)d_out;

  char* ws = (char*)d_ws;
  size_t cur = 0;
  auto alloc = [&](size_t bytes) -> char* {
    char* p = ws + cur;
    cur += (bytes + 255) & ~(size_t)255;
    return p;
  };
  float* sc1  = (float*)alloc(64 * 4);    float* sh1  = (float*)alloc(64 * 4);
  float* scSK = (float*)alloc(1024 * 4);  float* shSK = (float*)alloc(1024 * 4);
  float* scA1 = (float*)alloc(128 * 4);   float* shA1 = (float*)alloc(128 * 4);
  float* scA2 = (float*)alloc(128 * 4);   float* shA2 = (float*)alloc(128 * 4);
  float* scC1 = (float*)alloc(256 * 4);   float* shC1 = (float*)alloc(256 * 4);
  float* scC2 = (float*)alloc(256 * 4);   float* shC2 = (float*)alloc(256 * 4);
  float* scF  = (float*)alloc(512 * 4);   float* shF  = (float*)alloc(512 * 4);
  float* w1lT1 = (float*)alloc((size_t)64 * 128 * 4);
  float* w2T1  = (float*)alloc((size_t)128 * 128 * 4);
  float* w1lT2 = (float*)alloc((size_t)128 * 256 * 4);
  float* w2T2  = (float*)alloc((size_t)256 * 256 * 4);
  float* featT  = (float*)alloc((size_t)32 * 1024 * 64 * 4);
  float* xpre   = (float*)alloc((size_t)32 * 1024 * 256 * 4);
  int*   fidx1  = (int*)  alloc((size_t)32 * 512 * 4);
  float* nxyz1  = (float*)alloc((size_t)32 * 512 * 3 * 4);
  int*   knn1   = (int*)  alloc((size_t)32 * 512 * 32 * 4);
  int*   fidx2  = (int*)  alloc((size_t)32 * 256 * 4);
  float* nxyz2  = (float*)alloc((size_t)32 * 256 * 3 * 4);
  int*   knn2   = (int*)  alloc((size_t)32 * 256 * 32 * 4);
  float* part   = (float*)alloc((size_t)16384 * 128 * 2 * 4);  // == 8192*256*2, reused by stage 2
  float* pooledPre = (float*)alloc((size_t)16384 * 128 * 4);   // == 8192*256, reused by stage 2
  float* f0feat = (float*)alloc((size_t)16384 * 128 * 4);
  float* f1T    = (float*)alloc((size_t)32 * 256 * 256 * 4);
  float* finpre = (float*)alloc((size_t)32 * 512 * 256 * 4);

  if (cur > ws_size){
    float code = -1000.f - (float)(ws_size >> 20);
    kfb<<<(out_size + 255) / 256, 256, 0, stream>>>(out, out_size, code);
    return;
  }

  // weight transposes
  kprepT<<<(128 * 64 + 255) / 256, 256, 0, stream>>>(l0w1, 128, 64, 128, 0, w1lT1);
  kprepT<<<(128 * 128 + 255) / 256, 256, 0, stream>>>(l0w2, 128, 128, 128, 0, w2T1);
  kprepT<<<(256 * 128 + 255) / 256, 256, 0, stream>>>(l1w1, 256, 128, 256, 0, w1lT2);
  kprepT<<<(256 * 256 + 255) / 256, 256, 0, stream>>>(l1w2, 256, 256, 256, 0, w2T2);

  // stage A
  kA_stats<<<64, 256, 0, stream>>>(x, w_c1, g1, b1, sc1, sh1);
  kA_feat<<<128, 256, 0, stream>>>(x, w_c1, sc1, sh1, featT);

  // x_skip
  kxskip_pre<<<8192, 256, 0, stream>>>(featT, w_c2, xpre);
  kxskip_stats<<<1024, 256, 0, stream>>>(xpre, g2, b2, scSK, shSK);

  // stage 1 selections (butterfly, f32)
  kfps<1024, 512, 1><<<32, 64, 0, stream>>>(x, x + 1024, x + 2048, 6144, fidx1, nxyz1);
  kknn<1024, 512><<<32 * 512 / 4, 256, 0, stream>>>(x, x + 1024, x + 2048, 6144, 1, nxyz1, knn1);

  // stage 1 local_op
  kg1stats<64, 128, 1024, 9><<<16384, 256, 0, stream>>>(featT, knn1, fidx1, l0w1, w1lT1, part);
  kstats_part<128, 16384><<<128, 256, 0, stream>>>(part, l0g1, l0b1, scA1, shA1);
  kg2full<64, 128, 1024, 9><<<16384, 256, 0, stream>>>(featT, knn1, fidx1, l0w1, w1lT1, scA1, shA1, w2T1, l0g2, part, pooledPre);
  kstats_part<128, 16384><<<128, 256, 0, stream>>>(part, l0g2, l0b2, scA2, shA2);
  kpool_fin1<<<8192, 256, 0, stream>>>(pooledPre, scA2, shA2, f0feat);

  // stage 2 selections
  kfps<512, 256, 3><<<32, 64, 0, stream>>>(nxyz1, nxyz1 + 1, nxyz1 + 2, 1536, fidx2, nxyz2);
  kknn<512, 256><<<32 * 256 / 4, 256, 0, stream>>>(nxyz1, nxyz1 + 1, nxyz1 + 2, 1536, 3, nxyz2, knn2);

  // stage 2 local_op
  kg1stats<128, 256, 512, 8><<<8192, 256, 0, stream>>>(f0feat, knn2, fidx2, l1w1, w1lT2, part);
  kstats_part<256, 8192><<<256, 256, 0, stream>>>(part, l1g1, l1b1, scC1, shC1);
  kg2full<128, 256, 512, 8><<<8192, 256, 0, stream>>>(f0feat, knn2, fidx2, l1w1, w1lT2, scC1, shC1, w2T2, l1g2, part, pooledPre);
  kstats_part<256, 8192><<<256, 256, 0, stream>>>(part, l1g2, l1b2, scC2, shC2);
  kpool_finT<<<8192, 256, 0, stream>>>(pooledPre, scC2, shC2, f1T);

  // final
  kfinal8<<<2048, 256, 0, stream>>>(f1T, xpre, scSK, shSK, wf, finpre);
  kstats_fin<<<512, 256, 0, stream>>>(finpre, gf, bfp, scF, shF);
  kapply<<<16384, 256, 0, stream>>>(finpre, scF, shF, out);
}

// Round 10
// 3019.476 us; speedup vs baseline: 4.2218x; 1.3246x over previous
//
#include <hip/hip_runtime.h>
#include <stdint.h>

typedef unsigned int u32;
typedef unsigned short u16;
typedef __attribute__((ext_vector_type(8))) short bf16x8;   // 8 bf16 = 4 VGPRs
typedef __attribute__((ext_vector_type(4))) float f32x4;

#define DEV __device__ __forceinline__
#define BN_EPS 1e-5f

DEV u16 f2bf(float f){ u32 x = __float_as_uint(f); return (u16)((x + 0x7FFFu + ((x >> 16) & 1u)) >> 16); }

// ---------------------------------------------------------------- ws-too-small fallback
__global__ void kfb(float* out, int n, float code){
  int i = blockIdx.x * 256 + threadIdx.x;
  if (i < n) out[i] = (i == 0) ? code : 0.f;
}

// cast weights to bf16: dst[r*cols+c] = bf16(src[r*srcStride + colOff + c])
__global__ void kcast_bf(const float* __restrict__ src, int rows, int cols, int srcStride, int colOff,
                         u16* __restrict__ dst){
  int i = blockIdx.x * 256 + threadIdx.x;
  if (i >= rows * cols) return;
  int r = i / cols, c = i - r * cols;
  dst[r * cols + c] = f2bf(src[r * srcStride + colOff + c]);
}

// ---------------------------------------------------------------- stage A: BN1 stats (deterministic)
__global__ __launch_bounds__(256) void kA_stats(const float* __restrict__ x, const float* __restrict__ w,
                                                const float* __restrict__ g, const float* __restrict__ b,
                                                float* __restrict__ sc, float* __restrict__ sh){
  int c = blockIdx.x, t = threadIdx.x;
  float wr[6];
#pragma unroll
  for (int j = 0; j < 6; ++j) wr[j] = w[c * 6 + j];
  float s = 0.f, ss = 0.f;
  for (int i = t; i < 32768; i += 256){
    int bb = i >> 10, n = i & 1023;
    const float* xb = x + bb * 6144 + n;
    float y = 0.f;
#pragma unroll
    for (int j = 0; j < 6; ++j) y += wr[j] * xb[j * 1024];
    s += y; ss += y * y;
  }
  __shared__ float rs[256], rq[256];
  rs[t] = s; rq[t] = ss; __syncthreads();
  for (int k = 128; k >= 1; k >>= 1){
    if (t < k){ rs[t] += rs[t + k]; rq[t] += rq[t + k]; }
    __syncthreads();
  }
  if (t == 0){
    float m = rs[0] * (1.f / 32768.f), e2 = rq[0] * (1.f / 32768.f);
    float var = e2 - m * m; if (var < 0.f) var = 0.f;
    float scv = g[c] * rsqrtf(var + BN_EPS);
    sc[c] = scv; sh[c] = b[c] - m * scv;
  }
}

// stage A apply -> featT f32 [b][n][64]
__global__ __launch_bounds__(256) void kA_feat(const float* __restrict__ x, const float* __restrict__ w,
                                               const float* __restrict__ sc, const float* __restrict__ sh,
                                               float* __restrict__ featT){
  int b = blockIdx.x >> 2, t = threadIdx.x;
  int n = ((blockIdx.x & 3) << 8) + t;
  __shared__ float wl[384], scl[64], shl[64];
  for (int u = t; u < 384; u += 256) wl[u] = w[u];
  if (t < 64){ scl[t] = sc[t]; shl[t] = sh[t]; }
  __syncthreads();
  float v[6];
  const float* xb = x + b * 6144 + n;
#pragma unroll
  for (int j = 0; j < 6; ++j) v[j] = xb[j * 1024];
  float* row = featT + ((size_t)b * 1024 + n) * 64;
#pragma unroll
  for (int c = 0; c < 64; ++c){
    float y = 0.f;
#pragma unroll
    for (int j = 0; j < 6; ++j) y += wl[c * 6 + j] * v[j];
    y = scl[c] * y + shl[c];
    row[c] = fmaxf(y, 0.f);
  }
}

// ---------------------------------------------------------------- x_skip pre-act f32 [b][1024][256]
__global__ __launch_bounds__(256) void kxskip_pre(const float* __restrict__ featT, const float* __restrict__ w2,
                                                  float* __restrict__ xpre){
  int b = blockIdx.x >> 8, m = blockIdx.x & 255, t = threadIdx.x;
  __shared__ float row[64];
  if (t < 64) row[t] = featT[((size_t)b * 1024 + 4 * m) * 64 + t];
  __syncthreads();
#pragma unroll
  for (int rep = 0; rep < 4; ++rep){
    int o = rep * 256 + t;
    float acc = 0.f;
    const float* wr = w2 + (size_t)o * 64;
#pragma unroll
    for (int c = 0; c < 64; ++c) acc += wr[c] * row[c];
    xpre[((size_t)b * 1024 + o) * 256 + m] = acc;
  }
}

__global__ __launch_bounds__(256) void kxskip_stats(const float* __restrict__ xpre, const float* __restrict__ g,
                                                    const float* __restrict__ b, float* __restrict__ sc,
                                                    float* __restrict__ sh){
  int o = blockIdx.x, t = threadIdx.x;
  float s = 0.f, ss = 0.f;
  for (int i = t; i < 8192; i += 256){
    int bb = i >> 8, m = i & 255;
    float v = xpre[((size_t)bb * 1024 + o) * 256 + m];
    s += v; ss += v * v;
  }
  __shared__ float rs[256], rq[256];
  rs[t] = s; rq[t] = ss; __syncthreads();
  for (int k = 128; k >= 1; k >>= 1){
    if (t < k){ rs[t] += rs[t + k]; rq[t] += rq[t + k]; }
    __syncthreads();
  }
  if (t == 0){
    float m = rs[0] * (1.f / 8192.f), e2 = rq[0] * (1.f / 8192.f);
    float var = e2 - m * m; if (var < 0.f) var = 0.f;
    float scv = g[o] * rsqrtf(var + BN_EPS);
    sc[o] = scv; sh[o] = b[o] - m * scv;
  }
}

// ---------------------------------------------------------------- FPS: wave butterfly, f32 np-order
template<int NPTS, int NSAMP, int PSTRIDE>
__global__ __launch_bounds__(64) void kfps(const float* __restrict__ px_, const float* __restrict__ py_,
                                           const float* __restrict__ pz_, int bstride,
                                           int* __restrict__ fidx, float* __restrict__ nxyz){
  constexpr int PPL = NPTS / 64;
  int b = blockIdx.x, lane = threadIdx.x;
  const float* pxb = px_ + (size_t)b * bstride;
  const float* pyb = py_ + (size_t)b * bstride;
  const float* pzb = pz_ + (size_t)b * bstride;
  float px[PPL], py[PPL], pz[PPL], dd[PPL];
#pragma unroll
  for (int j = 0; j < PPL; ++j){
    int p = j * 64 + lane;
    px[j] = pxb[p * PSTRIDE]; py[j] = pyb[p * PSTRIDE]; pz[j] = pzb[p * PSTRIDE];
    dd[j] = 1e10f;
  }
  float cx = __shfl(px[0], 0, 64), cy = __shfl(py[0], 0, 64), cz = __shfl(pz[0], 0, 64);
  if (lane == 0){
    fidx[(size_t)b * NSAMP] = 0;
    nxyz[(size_t)b * NSAMP * 3 + 0] = cx;
    nxyz[(size_t)b * NSAMP * 3 + 1] = cy;
    nxyz[(size_t)b * NSAMP * 3 + 2] = cz;
  }
  for (int s = 1; s < NSAMP; ++s){
    float bd = -1.f; u32 bi = 0;
#pragma unroll
    for (int j = 0; j < PPL; ++j){
      float dx = __fsub_rn(px[j], cx);
      float dy = __fsub_rn(py[j], cy);
      float dz = __fsub_rn(pz[j], cz);
      float d = __fadd_rn(__fadd_rn(__fmul_rn(dx, dx), __fmul_rn(dy, dy)), __fmul_rn(dz, dz));
      float nd = fminf(dd[j], d);
      dd[j] = nd;
      u32 pi = (u32)(j * 64 + lane);
      if (nd > bd || (nd == bd && pi < bi)){ bd = nd; bi = pi; }
    }
#pragma unroll
    for (int o = 32; o >= 1; o >>= 1){
      float od = __shfl_xor(bd, o, 64);
      u32 oi = __shfl_xor(bi, o, 64);
      if (od > bd || (od == bd && oi < bi)){ bd = od; bi = oi; }
    }
    int wl = (int)(bi & 63u); int slot = (int)(bi >> 6);
    float sx = 0.f, sy = 0.f, sz = 0.f;
#pragma unroll
    for (int j = 0; j < PPL; ++j) if (slot == j){ sx = px[j]; sy = py[j]; sz = pz[j]; }
    cx = __shfl(sx, wl, 64); cy = __shfl(sy, wl, 64); cz = __shfl(sz, wl, 64);
    if (lane == 0){
      fidx[(size_t)b * NSAMP + s] = (int)bi;
      nxyz[((size_t)b * NSAMP + s) * 3 + 0] = cx;
      nxyz[((size_t)b * NSAMP + s) * 3 + 1] = cy;
      nxyz[((size_t)b * NSAMP + s) * 3 + 2] = cz;
    }
  }
}

// ---------------------------------------------------------------- kNN: wave butterfly, 4 waves/block
template<int NPTS, int SOUT>
__global__ __launch_bounds__(256) void kknn(const float* __restrict__ px_, const float* __restrict__ py_,
                                            const float* __restrict__ pz_, int bstride, int pstride,
                                            const float* __restrict__ cxyz, int* __restrict__ knn){
  constexpr int PPL = NPTS / 64;
  int wid = blockIdx.x * 4 + (threadIdx.x >> 6);
  int lane = threadIdx.x & 63;
  int b = wid / SOUT, s = wid - b * SOUT;
  const float* cb = cxyz + ((size_t)b * SOUT + s) * 3;
  float cx = cb[0], cy = cb[1], cz = cb[2];
  float csq = __fadd_rn(__fadd_rn(__fmul_rn(cx, cx), __fmul_rn(cy, cy)), __fmul_rn(cz, cz));
  float kd[PPL]; u32 kp[PPL];
#pragma unroll
  for (int j = 0; j < PPL; ++j){
    int p = j * 64 + lane;
    float xx = px_[(size_t)b * bstride + p * pstride];
    float yy = py_[(size_t)b * bstride + p * pstride];
    float zz = pz_[(size_t)b * bstride + p * pstride];
    float psq = __fadd_rn(__fadd_rn(__fmul_rn(xx, xx), __fmul_rn(yy, yy)), __fmul_rn(zz, zz));
    float dot = __fadd_rn(__fadd_rn(__fmul_rn(cx, xx), __fmul_rn(cy, yy)), __fmul_rn(cz, zz));
    kd[j] = __fsub_rn(__fadd_rn(csq, psq), __fmul_rn(2.f, dot));
    kp[j] = (u32)p;
  }
  int* outp = knn + ((size_t)b * SOUT + s) * 32;
  for (int k = 0; k < 32; ++k){
    float bd = kd[0]; u32 bp = kp[0];
#pragma unroll
    for (int j = 1; j < PPL; ++j){
      if (kd[j] < bd || (kd[j] == bd && kp[j] < bp)){ bd = kd[j]; bp = kp[j]; }
    }
#pragma unroll
    for (int o = 32; o >= 1; o >>= 1){
      float od = __shfl_xor(bd, o, 64);
      u32 op = __shfl_xor(bp, o, 64);
      if (od < bd || (od == bd && op < bp)){ bd = od; bp = op; }
    }
    if (lane == 0) outp[k] = (int)bp;
#pragma unroll
    for (int j = 0; j < PPL; ++j) if (kp[j] == bp) kd[j] = 3e38f;
  }
}

// ---------------------------------------------------------------- local_op via MFMA
// GEMM1: pre[o][k] = sum_c w1l[o][c]*(g[k][c]-cen[c]) + bias[o];  bias = sum_c w1r[o][c]*cen[c]
// FULL: + BN1+ReLU -> act2 (bf16 LDS) -> GEMM2 -> per-o sum/sumsq (+ pool by gamma sign)
// A/B fragments share the k-mapping k=(lane>>4)*8+i -> result invariant to HW k-order.
// C/D layout (verified m89): value(lane,reg j) = D[m=(lane>>4)*4+j][n=lane&15]
template<int CIN, int C, int NPTSRC, int SLOG, int FULL>
__global__ __launch_bounds__(256) void kgm(const float* __restrict__ featSrc, const int* __restrict__ knnIdx,
                                           const int* __restrict__ fidx, const float* __restrict__ w1f,
                                           const u16* __restrict__ w1bf,
                                           const float* __restrict__ sc1g, const float* __restrict__ sh1g,
                                           const u16* __restrict__ w2bf, const float* __restrict__ gp,
                                           float* __restrict__ part, float* __restrict__ pooledPre){
  constexpr int MT  = C / 64;        // M-tiles per wave (4 waves cover C rows)
  constexpr int KS1 = CIN / 32;
  constexpr int KS2 = C / 32;
  constexpr int P1  = CIN + 8;       // u16 pitch, rows 16B-aligned, ~2-way banks
  constexpr int P2  = C + 8;
  int g = blockIdx.x, t = threadIdx.x, b = g >> SLOG;
  int l = t & 63, wv = t >> 6;
  int lg = l >> 4, ln = l & 15;

  __shared__ int   idxs[32];
  __shared__ float cen[CIN];
  __shared__ float bias[C];
  __shared__ float sc1s[FULL ? C : 1], sh1s[FULL ? C : 1];
  __shared__ u16   gsT[32][P1];
  __shared__ u16   act2[FULL ? 32 : 1][FULL ? P2 : 1];

  if (t < 32) idxs[t] = knnIdx[(size_t)g * 32 + t];
  for (int u = t; u < CIN; u += 256) cen[u] = featSrc[((size_t)(b * NPTSRC + fidx[g])) * CIN + u];
  if (FULL && t < C){ sc1s[t] = sc1g[t]; sh1s[t] = sh1g[t]; }
  __syncthreads();

  // gather (g - cen) -> bf16 LDS [k][c]
  for (int u = t; u < 32 * CIN / 4; u += 256){
    int k = u & 31, c4 = u >> 5;
    float4 v = *(const float4*)(featSrc + ((size_t)(b * NPTSRC + idxs[k])) * CIN + c4 * 4);
    u16 b0 = f2bf(v.x - cen[c4 * 4 + 0]), b1 = f2bf(v.y - cen[c4 * 4 + 1]);
    u16 b2 = f2bf(v.z - cen[c4 * 4 + 2]), b3 = f2bf(v.w - cen[c4 * 4 + 3]);
    *(uint2*)&gsT[k][c4 * 4] = make_uint2((u32)b0 | ((u32)b1 << 16), (u32)b2 | ((u32)b3 << 16));
  }
  if (t < C){
    const float* wr = w1f + (size_t)t * (2 * CIN) + CIN;
    float bs = 0.f;
#pragma unroll 4
    for (int c = 0; c < CIN; ++c) bs += wr[c] * cen[c];
    bias[t] = bs;
  }
  __syncthreads();

  // -------- GEMM1 --------
  f32x4 acc[MT][2];
#pragma unroll
  for (int mt = 0; mt < MT; ++mt){ acc[mt][0] = (f32x4)0.f; acc[mt][1] = (f32x4)0.f; }
#pragma unroll
  for (int ks = 0; ks < KS1; ++ks){
    int c0 = ks * 32 + lg * 8;
    bf16x8 bfr0 = *(const bf16x8*)&gsT[ln][c0];
    bf16x8 bfr1 = *(const bf16x8*)&gsT[16 + ln][c0];
#pragma unroll
    for (int mt = 0; mt < MT; ++mt){
      int o0 = wv * (C / 4) + mt * 16;
      bf16x8 afr = *(const bf16x8*)(w1bf + (size_t)(o0 + ln) * CIN + c0);
      acc[mt][0] = __builtin_amdgcn_mfma_f32_16x16x32_bf16(afr, bfr0, acc[mt][0], 0, 0, 0);
      acc[mt][1] = __builtin_amdgcn_mfma_f32_16x16x32_bf16(afr, bfr1, acc[mt][1], 0, 0, 0);
    }
  }

  if (!FULL){
    // BN1 partial stats over pre = acc + bias
#pragma unroll
    for (int mt = 0; mt < MT; ++mt){
      int obase = wv * (C / 4) + mt * 16 + lg * 4;
#pragma unroll
      for (int j = 0; j < 4; ++j){
        float bv = bias[obase + j];
        float vA = acc[mt][0][j] + bv, vB = acc[mt][1][j] + bv;
        float s = vA + vB, ss = vA * vA + vB * vB;
#pragma unroll
        for (int mk = 1; mk < 16; mk <<= 1){ s += __shfl_xor(s, mk, 64); ss += __shfl_xor(ss, mk, 64); }
        if (ln == 0){
          part[((size_t)g * C + obase + j) * 2 + 0] = s;
          part[((size_t)g * C + obase + j) * 2 + 1] = ss;
        }
      }
    }
    return;
  }

  // BN1 + ReLU -> act2[k][o] bf16
#pragma unroll
  for (int mt = 0; mt < MT; ++mt){
    int obase = wv * (C / 4) + mt * 16 + lg * 4;
#pragma unroll
    for (int nt = 0; nt < 2; ++nt){
      u16 h[4];
#pragma unroll
      for (int j = 0; j < 4; ++j){
        int o = obase + j;
        float v = fmaxf(sc1s[o] * (acc[mt][nt][j] + bias[o]) + sh1s[o], 0.f);
        h[j] = f2bf(v);
      }
      *(uint2*)&act2[nt * 16 + ln][obase] =
          make_uint2((u32)h[0] | ((u32)h[1] << 16), (u32)h[2] | ((u32)h[3] << 16));
    }
  }
  __syncthreads();

  // -------- GEMM2 --------
#pragma unroll
  for (int mt = 0; mt < MT; ++mt){ acc[mt][0] = (f32x4)0.f; acc[mt][1] = (f32x4)0.f; }
#pragma unroll
  for (int ks = 0; ks < KS2; ++ks){
    int c0 = ks * 32 + lg * 8;
    bf16x8 bfr0 = *(const bf16x8*)&act2[ln][c0];
    bf16x8 bfr1 = *(const bf16x8*)&act2[16 + ln][c0];
#pragma unroll
    for (int mt = 0; mt < MT; ++mt){
      int o0 = wv * (C / 4) + mt * 16;
      bf16x8 afr = *(const bf16x8*)(w2bf + (size_t)(o0 + ln) * C + c0);
      acc[mt][0] = __builtin_amdgcn_mfma_f32_16x16x32_bf16(afr, bfr0, acc[mt][0], 0, 0, 0);
      acc[mt][1] = __builtin_amdgcn_mfma_f32_16x16x32_bf16(afr, bfr1, acc[mt][1], 0, 0, 0);
    }
  }

  // per-o reduce (sum, sumsq, max, min over 32 k) + pool
#pragma unroll
  for (int mt = 0; mt < MT; ++mt){
    int obase = wv * (C / 4) + mt * 16 + lg * 4;
#pragma unroll
    for (int j = 0; j < 4; ++j){
      float vA = acc[mt][0][j], vB = acc[mt][1][j];
      float s = vA + vB, ss = vA * vA + vB * vB;
      float mx = fmaxf(vA, vB), mn = fminf(vA, vB);
#pragma unroll
      for (int mk = 1; mk < 16; mk <<= 1){
        s += __shfl_xor(s, mk, 64); ss += __shfl_xor(ss, mk, 64);
        mx = fmaxf(mx, __shfl_xor(mx, mk, 64)); mn = fminf(mn, __shfl_xor(mn, mk, 64));
      }
      if (ln == 0){
        int o = obase + j;
        part[((size_t)g * C + o) * 2 + 0] = s;
        part[((size_t)g * C + o) * 2 + 1] = ss;
        pooledPre[(size_t)g * C + o] = (gp[o] >= 0.f) ? mx : mn;
      }
    }
  }
}

// reduce per-group partials -> BN scale/shift (deterministic)
template<int C, int NG>
__global__ __launch_bounds__(256) void kstats_part(const float* __restrict__ part, const float* __restrict__ g_,
                                                   const float* __restrict__ b_, float* __restrict__ sc,
                                                   float* __restrict__ sh){
  int o = blockIdx.x, t = threadIdx.x;
  float s = 0.f, ss = 0.f;
  for (int i = t; i < NG; i += 256){
    s  += part[((size_t)i * C + o) * 2 + 0];
    ss += part[((size_t)i * C + o) * 2 + 1];
  }
  __shared__ float rs[256], rq[256];
  rs[t] = s; rq[t] = ss; __syncthreads();
  for (int k = 128; k >= 1; k >>= 1){
    if (t < k){ rs[t] += rs[t + k]; rq[t] += rq[t + k]; }
    __syncthreads();
  }
  if (t == 0){
    const float inv_n = 1.f / (float)(NG * 32);
    float m = rs[0] * inv_n, e2 = rq[0] * inv_n;
    float var = e2 - m * m; if (var < 0.f) var = 0.f;
    float scv = g_[o] * rsqrtf(var + BN_EPS);
    sc[o] = scv; sh[o] = b_[o] - m * scv;
  }
}

// finalize pooled (stage1): f0feat f32 [b*512+s][128]
__global__ void kpool_fin1(const float* __restrict__ pooledPre, const float* __restrict__ sc,
                           const float* __restrict__ sh, float* __restrict__ f0feat){
  int i = blockIdx.x * 256 + threadIdx.x;
  if (i >= 16384 * 128) return;
  int o = i & 127;
  float v = sc[o] * pooledPre[i] + sh[o];
  f0feat[i] = fmaxf(v, 0.f);
}

// finalize pooled (stage2): f1T f32 [b][c][s]
__global__ void kpool_finT(const float* __restrict__ pooledPre, const float* __restrict__ sc,
                           const float* __restrict__ sh, float* __restrict__ f1T){
  int i = blockIdx.x * 256 + threadIdx.x;
  if (i >= 8192 * 256) return;
  int gg = i >> 8, o = i & 255;
  int b = gg >> 8, s = gg & 255;
  float v = sc[o] * pooledPre[i] + sh[o];
  f1T[((size_t)(b * 256 + o)) * 256 + s] = fmaxf(v, 0.f);
}

// ---------------------------------------------------------------- final GEMM: block = (b, 8-o tile), thread = m
__global__ __launch_bounds__(256) void kfinal8(const float* __restrict__ f1T, const float* __restrict__ xpre,
                                               const float* __restrict__ scS, const float* __restrict__ shS,
                                               const float* __restrict__ wf, float* __restrict__ finpre){
  int b = blockIdx.x >> 6, ot = blockIdx.x & 63, m = threadIdx.x;
  int o0 = ot * 8;
  const float* wb = wf + (size_t)o0 * 1280;
  float acc[8];
#pragma unroll
  for (int j = 0; j < 8; ++j) acc[j] = 0.f;
  const float* fb = f1T + (size_t)b * 256 * 256 + m;
  for (int k = 0; k < 256; ++k){
    float v = fb[(size_t)k * 256];
#pragma unroll
    for (int j = 0; j < 8; ++j) acc[j] = fmaf(wb[(size_t)j * 1280 + k], v, acc[j]);
  }
  const float* xb = xpre + (size_t)b * 1024 * 256 + m;
  for (int k = 0; k < 1024; ++k){
    float xv = xb[(size_t)k * 256];
    float v = fmaxf(scS[k] * xv + shS[k], 0.f);
#pragma unroll
    for (int j = 0; j < 8; ++j) acc[j] = fmaf(wb[(size_t)j * 1280 + 256 + k], v, acc[j]);
  }
#pragma unroll
  for (int j = 0; j < 8; ++j)
    finpre[((size_t)b * 512 + o0 + j) * 256 + m] = acc[j];
}

__global__ __launch_bounds__(256) void kstats_fin(const float* __restrict__ finpre, const float* __restrict__ g,
                                                  const float* __restrict__ b, float* __restrict__ sc,
                                                  float* __restrict__ sh){
  int o = blockIdx.x, t = threadIdx.x;
  float s = 0.f, ss = 0.f;
  for (int i = t; i < 8192; i += 256){
    int bb = i >> 8, m = i & 255;
    float v = finpre[((size_t)bb * 512 + o) * 256 + m];
    s += v; ss += v * v;
  }
  __shared__ float rs[256], rq[256];
  rs[t] = s; rq[t] = ss; __syncthreads();
  for (int k = 128; k >= 1; k >>= 1){
    if (t < k){ rs[t] += rs[t + k]; rq[t] += rq[t + k]; }
    __syncthreads();
  }
  if (t == 0){
    float m = rs[0] * (1.f / 8192.f), e2 = rq[0] * (1.f / 8192.f);
    float var = e2 - m * m; if (var < 0.f) var = 0.f;
    float scv = g[o] * rsqrtf(var + BN_EPS);
    sc[o] = scv; sh[o] = b[o] - m * scv;
  }
}

__global__ void kapply(const float* __restrict__ finpre, const float* __restrict__ sc,
                       const float* __restrict__ sh, float* __restrict__ out){
  int i = blockIdx.x * 256 + threadIdx.x;
  if (i >= 32 * 512 * 256) return;
  int o = (i >> 8) & 511;
  float v = sc[o] * finpre[i] + sh[o];
  out[i] = v > 0.f ? v : 0.2f * v;
}

// ================================================================ host
extern "C" void kernel_launch(void* const* d_in, const int* in_sizes, int n_in,
                              void* d_out, int out_size, void* d_ws, size_t ws_size,
                              hipStream_t stream){
  const float* x    = (const float*)d_in[0];
  const float* w_c1 = (const float*)d_in[1];
  const float* g1   = (const float*)d_in[2];
  const float* b1   = (const float*)d_in[3];
  const float* w_c2 = (const float*)d_in[4];
  const float* g2   = (const float*)d_in[5];
  const float* b2   = (const float*)d_in[6];
  const float* l0w1 = (const float*)d_in[7];
  const float* l0g1 = (const float*)d_in[8];
  const float* l0b1 = (const float*)d_in[9];
  const float* l0w2 = (const float*)d_in[10];
  const float* l0g2 = (const float*)d_in[11];
  const float* l0b2 = (const float*)d_in[12];
  const float* l1w1 = (const float*)d_in[13];
  const float* l1g1 = (const float*)d_in[14];
  const float* l1b1 = (const float*)d_in[15];
  const float* l1w2 = (const float*)d_in[16];
  const float* l1g2 = (const float*)d_in[17];
  const float* l1b2 = (const float*)d_in[18];
  const float* wf   = (const float*)d_in[19];
  const float* gf   = (const float*)d_in[20];
  const float* bfp  = (const float*)d_in[21];
  float* out = (float*)d_out;

  char* ws = (char*)d_ws;
  size_t cur = 0;
  auto alloc = [&](size_t bytes) -> char* {
    char* p = ws + cur;
    cur += (bytes + 255) & ~(size_t)255;
    return p;
  };
  float* sc1  = (float*)alloc(64 * 4);    float* sh1  = (float*)alloc(64 * 4);
  float* scSK = (float*)alloc(1024 * 4);  float* shSK = (float*)alloc(1024 * 4);
  float* scA1 = (float*)alloc(128 * 4);   float* shA1 = (float*)alloc(128 * 4);
  float* scA2 = (float*)alloc(128 * 4);   float* shA2 = (float*)alloc(128 * 4);
  float* scC1 = (float*)alloc(256 * 4);   float* shC1 = (float*)alloc(256 * 4);
  float* scC2 = (float*)alloc(256 * 4);   float* shC2 = (float*)alloc(256 * 4);
  float* scF  = (float*)alloc(512 * 4);   float* shF  = (float*)alloc(512 * 4);
  u16* w1bf1 = (u16*)alloc((size_t)128 * 64 * 2);
  u16* w2bf1 = (u16*)alloc((size_t)128 * 128 * 2);
  u16* w1bf2 = (u16*)alloc((size_t)256 * 128 * 2);
  u16* w2bf2 = (u16*)alloc((size_t)256 * 256 * 2);
  float* featT  = (float*)alloc((size_t)32 * 1024 * 64 * 4);
  float* xpre   = (float*)alloc((size_t)32 * 1024 * 256 * 4);
  int*   fidx1  = (int*)  alloc((size_t)32 * 512 * 4);
  float* nxyz1  = (float*)alloc((size_t)32 * 512 * 3 * 4);
  int*   knn1   = (int*)  alloc((size_t)32 * 512 * 32 * 4);
  int*   fidx2  = (int*)  alloc((size_t)32 * 256 * 4);
  float* nxyz2  = (float*)alloc((size_t)32 * 256 * 3 * 4);
  int*   knn2   = (int*)  alloc((size_t)32 * 256 * 32 * 4);
  float* part   = (float*)alloc((size_t)16384 * 128 * 2 * 4);  // == 8192*256*2, reused by stage 2
  float* pooledPre = (float*)alloc((size_t)16384 * 128 * 4);   // == 8192*256, reused by stage 2
  float* f0feat = (float*)alloc((size_t)16384 * 128 * 4);
  float* f1T    = (float*)alloc((size_t)32 * 256 * 256 * 4);
  float* finpre = (float*)alloc((size_t)32 * 512 * 256 * 4);

  if (cur > ws_size){
    float code = -1000.f - (float)(ws_size >> 20);
    kfb<<<(out_size + 255) / 256, 256, 0, stream>>>(out, out_size, code);
    return;
  }

  // bf16 weight casts (left half of w1; full w2)
  kcast_bf<<<(128 * 64 + 255) / 256, 256, 0, stream>>>(l0w1, 128, 64, 128, 0, w1bf1);
  kcast_bf<<<(128 * 128 + 255) / 256, 256, 0, stream>>>(l0w2, 128, 128, 128, 0, w2bf1);
  kcast_bf<<<(256 * 128 + 255) / 256, 256, 0, stream>>>(l1w1, 256, 128, 256, 0, w1bf2);
  kcast_bf<<<(256 * 256 + 255) / 256, 256, 0, stream>>>(l1w2, 256, 256, 256, 0, w2bf2);

  // stage A
  kA_stats<<<64, 256, 0, stream>>>(x, w_c1, g1, b1, sc1, sh1);
  kA_feat<<<128, 256, 0, stream>>>(x, w_c1, sc1, sh1, featT);

  // x_skip
  kxskip_pre<<<8192, 256, 0, stream>>>(featT, w_c2, xpre);
  kxskip_stats<<<1024, 256, 0, stream>>>(xpre, g2, b2, scSK, shSK);

  // stage 1 selections
  kfps<1024, 512, 1><<<32, 64, 0, stream>>>(x, x + 1024, x + 2048, 6144, fidx1, nxyz1);
  kknn<1024, 512><<<32 * 512 / 4, 256, 0, stream>>>(x, x + 1024, x + 2048, 6144, 1, nxyz1, knn1);

  // stage 1 local_op (MFMA)
  kgm<64, 128, 1024, 9, 0><<<16384, 256, 0, stream>>>(featT, knn1, fidx1, l0w1, w1bf1,
                                                      nullptr, nullptr, nullptr, nullptr, part, nullptr);
  kstats_part<128, 16384><<<128, 256, 0, stream>>>(part, l0g1, l0b1, scA1, shA1);
  kgm<64, 128, 1024, 9, 1><<<16384, 256, 0, stream>>>(featT, knn1, fidx1, l0w1, w1bf1,
                                                      scA1, shA1, w2bf1, l0g2, part, pooledPre);
  kstats_part<128, 16384><<<128, 256, 0, stream>>>(part, l0g2, l0b2, scA2, shA2);
  kpool_fin1<<<8192, 256, 0, stream>>>(pooledPre, scA2, shA2, f0feat);

  // stage 2 selections
  kfps<512, 256, 3><<<32, 64, 0, stream>>>(nxyz1, nxyz1 + 1, nxyz1 + 2, 1536, fidx2, nxyz2);
  kknn<512, 256><<<32 * 256 / 4, 256, 0, stream>>>(nxyz1, nxyz1 + 1, nxyz1 + 2, 1536, 3, nxyz2, knn2);

  // stage 2 local_op (MFMA)
  kgm<128, 256, 512, 8, 0><<<8192, 256, 0, stream>>>(f0feat, knn2, fidx2, l1w1, w1bf2,
                                                     nullptr, nullptr, nullptr, nullptr, part, nullptr);
  kstats_part<256, 8192><<<256, 256, 0, stream>>>(part, l1g1, l1b1, scC1, shC1);
  kgm<128, 256, 512, 8, 1><<<8192, 256, 0, stream>>>(f0feat, knn2, fidx2, l1w1, w1bf2,
                                                     scC1, shC1, w2bf2, l1g2, part, pooledPre);
  kstats_part<256, 8192><<<256, 256, 0, stream>>>(part, l1g2, l1b2, scC2, shC2);
  kpool_finT<<<8192, 256, 0, stream>>>(pooledPre, scC2, shC2, f1T);

  // final
  kfinal8<<<2048, 256, 0, stream>>>(f1T, xpre, scSK, shSK, wf, finpre);
  kstats_fin<<<512, 256, 0, stream>>>(finpre, gf, bfp, scF, shF);
  kapply<<<16384, 256, 0, stream>>>(finpre, scF, shF, out);
}